// Round 7
// baseline (1224.381 us; speedup 1.0000x reference)
//
#include <hip/hip_runtime.h>
#include <math.h>

// Problem constants (B=16, T=2000, E=1024, K=2048)
#define N_ROWS 32000
#define DIM    1024
#define NCENT  2048
#define MROWS  128           // x rows per block (main kernel)
#define NKP    512           // centroids per k-pass (two 256-k G tiles per chunk)
#define NPASS  (NCENT / NKP) // 4
#define KE     16            // e per staged chunk
#define NCHUNK (DIM / KE)    // 64 chunks per pass
#define NTHR   512           // 8 waves: each owns 64 centroids x 128 rows
#define TAU    0.015625f     // rescore margin (1/64, ~60 sigma of f16-split error)
// fallback-kernel constants
#define MROWS_FB 64
#define CS_KK  257
#define XS_KK  65

typedef _Float16 half4v __attribute__((ext_vector_type(4)));
typedef _Float16 half8v __attribute__((ext_vector_type(8)));
typedef float    floatx16 __attribute__((ext_vector_type(16)));

// Split a float4 into hi/lo f16 halves (RNE).
__device__ __forceinline__ void split4_f16(const float4 v, half4v& h, half4v& l) {
  const float f[4] = {v.x, v.y, v.z, v.w};
#pragma unroll
  for (int c = 0; c < 4; ++c) {
    const _Float16 hh = (_Float16)f[c];
    h[c] = hh;
    l[c] = (_Float16)(f[c] - (float)hh);
  }
}

// 16B global -> LDS DMA (wave-uniform LDS base + lane*16; our dest is linear in t).
__device__ __forceinline__ void gload_lds16(const _Float16* g, _Float16* l) {
  __builtin_amdgcn_global_load_lds(
      (const __attribute__((address_space(1))) void*)g,
      (__attribute__((address_space(3))) void*)l, 16, 0, 0);
}

// ---------------------------------------------------------------------------
// Pre-pass (UNCHANGED layout): split centroids once into the MFMA A-frag
// layout, tile-contiguous per (256-k group, chunk); exact fp32 norms once.
// G layout: tile g = (p256*64+ec) = 8192 halfs (16 KB); within tile:
//   idx = ((part*2 + esub)*256 + kk)*8 + j   (part 0=hi 1=lo, esub=(e%16)>>3,
//   kk = k%256, j = e%8). A-frag read = 8 contiguous f16 per lane.
// ---------------------------------------------------------------------------
__global__ void __launch_bounds__(256) kmeans_prep_kernel(
    const float* __restrict__ cent, _Float16* __restrict__ G,
    float* __restrict__ nrm_g) {
  const int k = blockIdx.x;       // centroid id
  const int t = threadIdx.x;      // owns float4 at e = 4t
  const float4 v = *(const float4*)(cent + (size_t)k * DIM + 4 * t);
  half4v h, l;
  split4_f16(v, h, l);
  const int e0 = 4 * t;
  const int p = k >> 8, kk = k & 255;
  const int ec = e0 >> 4, esub = (e0 >> 3) & 1, j = e0 & 7;  // j in {0,4}
  _Float16* tile = G + ((size_t)(p * NCHUNK + ec) << 13);
  *(half4v*)&tile[((0 * 2 + esub) * 256 + kk) * 8 + j] = h;
  *(half4v*)&tile[((1 * 2 + esub) * 256 + kk) * 8 + j] = l;

  float n = fmaf(v.x, v.x, fmaf(v.y, v.y, fmaf(v.z, v.z, v.w * v.w)));
  n += __shfl_xor(n, 1, 64);
  n += __shfl_xor(n, 2, 64);
  n += __shfl_xor(n, 4, 64);
  n += __shfl_xor(n, 8, 64);
  n += __shfl_xor(n, 16, 64);
  n += __shfl_xor(n, 32, 64);
  __shared__ float sn[4];
  if ((t & 63) == 0) sn[t >> 6] = n;
  __syncthreads();
  if (t == 0) nrm_g[k] = (sn[0] + sn[1]) + (sn[2] + sn[3]);
}

// ---------------------------------------------------------------------------
// Main kernel: 128 rows/block, 8 waves, NKP=512. Grid = 250 -> 1 block/CU,
// ONE generation, 256 barrier intervals. Per-CU staged bytes: G 8MB + x 2MB
// (vs 15.6MB at MROWS=64 with 500 blocks). Each wave: 64 centroids x 128
// rows (acc 2x4 f32x16 = 128 VGPR), 24 MFMA per chunk. Double-buffered
// KE=16 chunks; centroid DMA + x-load at head, x split+store write-late,
// one barrier per chunk.
// mfma_f32_32x32x16_f16: A[m=k][e], B[e][n=row],
// D: col(n)=lane&31, row(m)=(reg&3)+8*(reg>>2)+4*(lane>>5).
// ---------------------------------------------------------------------------
__global__ void __launch_bounds__(512, 2) kmeans_main_kernel(
    const float* __restrict__ x, const _Float16* __restrict__ G,
    const float* __restrict__ nrm_g, const float* __restrict__ cent,
    int* __restrict__ out) {
  __shared__ __align__(16) _Float16 cs[2][16384];  // 64 KB: [buf][khalf*8192 + ((part*2+esub)*256+kk)*8+j]
  __shared__ __align__(16) _Float16 xs[2][4][128][8];  // 16 KB: [buf][part*2+esub][row][j]
  __shared__ float sbest[MROWS][8];
  __shared__ float sbest2[MROWS][8];
  __shared__ int   sbidx[MROWS][8];
  __shared__ int   sres[MROWS];
  __shared__ int   sflag[MROWS];
  __shared__ float p2d[8];
  __shared__ int   p2k[8];

  const int t    = threadIdx.x;
  const int lane = t & 63;
  const int w    = t >> 6;      // wave 0..7 -> 64-centroid slice within pass
  const int l31  = lane & 31;
  const int lhi  = lane >> 5;   // 0/1
  const size_t row0 = (size_t)blockIdx.x * MROWS;

  // x staging geometry: 128 rows x 16 e = 512 float4 = 1 per thread.
  const int xrow  = t >> 2, xe4 = t & 3;
  const int xesub = xe4 >> 1, xj = (xe4 & 1) * 4;
  const float* xsrc = x + (row0 + xrow) * DIM + 4 * xe4;

  float best[4]  = {INFINITY, INFINITY, INFINITY, INFINITY};
  float best2[4] = {INFINITY, INFINITY, INFINITY, INFINITY};
  int   bidx[4]  = {0, 0, 0, 0};

  for (int p = 0; p < NPASS; ++p) {
    const int kbase = p * NKP;
    floatx16 acc[2][4] = {};   // [kt][nt]

    auto do_mfma = [&](int b) {
      const _Float16* cb = &cs[b][0];
      const _Float16* xb = &xs[b][0][0][0];
      half8v Ah[2], Al[2];
#pragma unroll
      for (int kt = 0; kt < 2; ++kt) {
        const int ks = w * 64 + kt * 32 + l31;     // k within pass [0,512)
        const int toff = (ks >> 8) * 8192;         // which 16-KB G tile half
        const int kk = ks & 255;
        Ah[kt] = *(const half8v*)&cb[toff + (lhi * 256 + kk) * 8];        // hi
        Al[kt] = *(const half8v*)&cb[toff + ((2 + lhi) * 256 + kk) * 8];  // lo
      }
      __builtin_amdgcn_s_setprio(1);
#pragma unroll
      for (int nt = 0; nt < 4; ++nt) {
        const int rr = nt * 32 + l31;
        const half8v Bh = *(const half8v*)&xb[(lhi * 128 + rr) * 8];
        const half8v Bl = *(const half8v*)&xb[((2 + lhi) * 128 + rr) * 8];
#pragma unroll
        for (int kt = 0; kt < 2; ++kt) {
          acc[kt][nt] = __builtin_amdgcn_mfma_f32_32x32x16_f16(Ah[kt], Bh, acc[kt][nt], 0, 0, 0);
          acc[kt][nt] = __builtin_amdgcn_mfma_f32_32x32x16_f16(Ah[kt], Bl, acc[kt][nt], 0, 0, 0);
          acc[kt][nt] = __builtin_amdgcn_mfma_f32_32x32x16_f16(Al[kt], Bh, acc[kt][nt], 0, 0, 0);
        }
      }
      __builtin_amdgcn_s_setprio(0);
    };

    __syncthreads();  // previous pass fully done before buffer overwrite

    // Prologue: stage chunk 0 into buffer 0 (two k-half tiles + x).
    {
      const _Float16* gt = G + ((size_t)(p * 2 * NCHUNK) << 13);
#pragma unroll
      for (int i = 0; i < 2; ++i) {
        gload_lds16(gt + t * 8 + i * 4096, &cs[0][t * 8 + i * 4096]);
        gload_lds16(gt + (64 << 13) + t * 8 + i * 4096,
                    &cs[0][8192 + t * 8 + i * 4096]);
      }
      const float4 xv = *(const float4*)(xsrc);
      half4v h, l;
      split4_f16(xv, h, l);
      *(half4v*)&xs[0][0 * 2 + xesub][xrow][xj] = h;
      *(half4v*)&xs[0][1 * 2 + xesub][xrow][xj] = l;
    }
    __syncthreads();  // chunk 0 resident

    int cur = 0;
    for (int ec = 0; ec < NCHUNK - 1; ++ec) {
      const int nb = cur ^ 1;
      // Issue next chunk's loads FIRST (latency hides under the MFMAs).
      const _Float16* gt = G + ((size_t)(p * 2 * NCHUNK + ec + 1) << 13);
#pragma unroll
      for (int i = 0; i < 2; ++i) {
        gload_lds16(gt + t * 8 + i * 4096, &cs[nb][t * 8 + i * 4096]);
        gload_lds16(gt + (64 << 13) + t * 8 + i * 4096,
                    &cs[nb][8192 + t * 8 + i * 4096]);
      }
      const float4 xn = *(const float4*)(xsrc + (ec + 1) * KE);

      do_mfma(cur);

      // Write-late: split+store x for next chunk after compute.
      {
        half4v h, l;
        split4_f16(xn, h, l);
        *(half4v*)&xs[nb][0 * 2 + xesub][xrow][xj] = h;
        *(half4v*)&xs[nb][1 * 2 + xesub][xrow][xj] = l;
      }
      __syncthreads();  // drains gload_lds (vmcnt) + ds writes; next chunk ready
      cur = nb;
    }
    do_mfma(cur);  // tail chunk (no prefetch)

    // Pass epilogue: d = nrm[k] - 2*dot; norms read straight from global
    // (L2-resident 8 KB -- off the critical path).
    {
      const int kmb = w * 64 + 4 * lhi;
#pragma unroll
      for (int kt = 0; kt < 2; ++kt) {
#pragma unroll
        for (int r = 0; r < 16; ++r) {
          const int km = kmb + kt * 32 + (r & 3) + 8 * (r >> 2);
          const int kg = kbase + km;
          const float nk = nrm_g[kg];
#pragma unroll
          for (int nt = 0; nt < 4; ++nt) {
            const float d = fmaf(-2.0f, acc[kt][nt][r], nk);
            if (d < best[nt]) { best2[nt] = best[nt]; best[nt] = d; bidx[nt] = kg; }
            else best2[nt] = fminf(best2[nt], d);
          }
        }
      }
    }
  }

  // Merge lane halves (l, l^32) then write per-wave row candidates.
#pragma unroll
  for (int nt = 0; nt < 4; ++nt) {
    float b = best[nt], b2 = best2[nt];
    int bi = bidx[nt];
    const float ob  = __shfl_xor(b, 32, 64);
    const float ob2 = __shfl_xor(b2, 32, 64);
    const int   obi = __shfl_xor(bi, 32, 64);
    const float nb2 = fminf(fminf(b2, ob2), fmaxf(b, ob));
    if (ob < b || (ob == b && obi < bi)) { b = ob; bi = obi; }
    if (lhi == 0) {
      const int row = nt * 32 + l31;
      sbest[row][w] = b; sbest2[row][w] = nb2; sbidx[row][w] = bi;
    }
  }
  __syncthreads();

  if (t < MROWS) {
    float b = sbest[t][0], b2 = sbest2[t][0];
    int bi = sbidx[t][0];
#pragma unroll
    for (int ww = 1; ww < 8; ++ww) {
      const float cb = sbest[t][ww], cb2 = sbest2[t][ww];
      const int cbi = sbidx[t][ww];
      const float nb2 = fminf(fminf(b2, cb2), fmaxf(b, cb));
      if (cb < b || (cb == b && cbi < bi)) { b = cb; bi = cbi; }
      b2 = nb2;
    }
    sres[t] = bi;
    sflag[t] = (b2 - b < TAU) ? 1 : 0;
  }
  __syncthreads();

  // Phase 2: exact fp32 rescore of flagged rows (expected ~0-1 per ~25 blocks).
  float* xrw = (float*)&xs[0][0][0][0];  // 4 KB fp32 scratch, reuses xs
  for (int r = 0; r < MROWS; ++r) {
    if (sflag[r]) {               // uniform branch (same LDS word for all threads)
      __syncthreads();
      for (int i = t; i < DIM / 4; i += NTHR)
        ((float4*)xrw)[i] = *(const float4*)(x + (row0 + r) * DIM + 4 * i);
      __syncthreads();
      float bd = INFINITY; int bk = NCENT;
      for (int i = 0; i < NCENT / NTHR; ++i) {
        const int k = t + NTHR * i;
        const float4* crow = (const float4*)(cent + (size_t)k * DIM);
        float a0 = 0.f, a1 = 0.f, a2 = 0.f, a3 = 0.f;
        float n0 = 0.f, n1 = 0.f, n2 = 0.f, n3 = 0.f;
#pragma unroll 8
        for (int j = 0; j < DIM / 4; ++j) {
          const float4 cv = crow[j];
          const float4 xv = ((const float4*)xrw)[j];
          a0 = fmaf(cv.x, xv.x, a0); n0 = fmaf(cv.x, cv.x, n0);
          a1 = fmaf(cv.y, xv.y, a1); n1 = fmaf(cv.y, cv.y, n1);
          a2 = fmaf(cv.z, xv.z, a2); n2 = fmaf(cv.z, cv.z, n2);
          a3 = fmaf(cv.w, xv.w, a3); n3 = fmaf(cv.w, cv.w, n3);
        }
        const float d = fmaf(-2.f, (a0 + a1) + (a2 + a3), (n0 + n1) + (n2 + n3));
        if (d < bd || (d == bd && k < bk)) { bd = d; bk = k; }
      }
#pragma unroll
      for (int off = 32; off > 0; off >>= 1) {
        const float od = __shfl_down(bd, off, 64);
        const int   ok = __shfl_down(bk, off, 64);
        if (od < bd || (od == bd && ok < bk)) { bd = od; bk = ok; }
      }
      if (lane == 0) { p2d[w] = bd; p2k[w] = bk; }
      __syncthreads();
      if (t == 0) {
        float fd = p2d[0]; int fk = p2k[0];
#pragma unroll
        for (int ww = 1; ww < 8; ++ww) {
          if (p2d[ww] < fd || (p2d[ww] == fd && p2k[ww] < fk)) {
            fd = p2d[ww]; fk = p2k[ww];
          }
        }
        sres[r] = fk;
      }
      __syncthreads();
    }
  }
  __syncthreads();

  if (t < MROWS) out[row0 + t] = sres[t];
}

// ---------------------------------------------------------------------------
// Fallback (verified, in-kernel split, 64 rows/block, KE=32) — used only if
// the workspace is too small for the pre-split centroid buffer.
// ---------------------------------------------------------------------------
__global__ void __launch_bounds__(256, 2) kmeans_mfma_fallback(
    const float* __restrict__ x, const float* __restrict__ cent,
    int* __restrict__ out) {
  __shared__ __align__(16) _Float16 cs[2][4][CS_KK][8];
  __shared__ __align__(16) _Float16 xs[2][4][XS_KK][8];
  __shared__ float nrm[256];
  __shared__ float sbest[MROWS_FB][4];
  __shared__ float sbest2[MROWS_FB][4];
  __shared__ int   sbidx[MROWS_FB][4];
  __shared__ int   sres[MROWS_FB];
  __shared__ int   sflag[MROWS_FB];
  __shared__ float p2d[4];
  __shared__ int   p2k[4];

  const int t    = threadIdx.x;
  const int lane = t & 63;
  const int w    = t >> 6;
  const int l31  = lane & 31;
  const int lhi  = lane >> 5;
  const size_t row0 = (size_t)blockIdx.x * MROWS_FB;

  float best[2]  = {INFINITY, INFINITY};
  float best2[2] = {INFINITY, INFINITY};
  int   bidx[2]  = {0, 0};

  for (int p = 0; p < 8; ++p) {
    const int kbase = p * 256;
    floatx16 acc[2][2] = {};
    float nacc[8] = {};

    for (int ec = 0; ec < 32; ++ec) {
      const int ebase = ec * 32;
      __syncthreads();
#pragma unroll
      for (int i = 0; i < 2; ++i) {
        const int idx = t + 256 * i;
        const int row = idx >> 3, e4 = idx & 7;
        const float4 v = *(const float4*)(x + (row0 + row) * DIM + ebase + 4 * e4);
        half4v h, l;
        split4_f16(v, h, l);
        *(half4v*)&xs[0][e4 >> 1][row][(e4 & 1) * 4] = h;
        *(half4v*)&xs[1][e4 >> 1][row][(e4 & 1) * 4] = l;
      }
#pragma unroll
      for (int i = 0; i < 8; ++i) {
        const int idx = t + 256 * i;
        const int kk = idx >> 3, e4 = idx & 7;
        const float4 v =
            *(const float4*)(cent + (size_t)(kbase + kk) * DIM + ebase + 4 * e4);
        nacc[i] = fmaf(v.x, v.x, nacc[i]); nacc[i] = fmaf(v.y, v.y, nacc[i]);
        nacc[i] = fmaf(v.z, v.z, nacc[i]); nacc[i] = fmaf(v.w, v.w, nacc[i]);
        half4v h, l;
        split4_f16(v, h, l);
        *(half4v*)&cs[0][e4 >> 1][kk][(e4 & 1) * 4] = h;
        *(half4v*)&cs[1][e4 >> 1][kk][(e4 & 1) * 4] = l;
      }
      __syncthreads();

#pragma unroll
      for (int es = 0; es < 2; ++es) {
        const int esub = es * 2 + lhi;
        half8v Ah[2], Al[2], Bh[2], Bl[2];
#pragma unroll
        for (int kt = 0; kt < 2; ++kt) {
          const int kk = w * 64 + kt * 32 + l31;
          Ah[kt] = *(const half8v*)&cs[0][esub][kk][0];
          Al[kt] = *(const half8v*)&cs[1][esub][kk][0];
        }
#pragma unroll
        for (int nt = 0; nt < 2; ++nt) {
          const int rr = nt * 32 + l31;
          Bh[nt] = *(const half8v*)&xs[0][esub][rr][0];
          Bl[nt] = *(const half8v*)&xs[1][esub][rr][0];
        }
#pragma unroll
        for (int kt = 0; kt < 2; ++kt)
#pragma unroll
          for (int nt = 0; nt < 2; ++nt) {
            acc[kt][nt] = __builtin_amdgcn_mfma_f32_32x32x16_f16(
                Ah[kt], Bh[nt], acc[kt][nt], 0, 0, 0);
            acc[kt][nt] = __builtin_amdgcn_mfma_f32_32x32x16_f16(
                Ah[kt], Bl[nt], acc[kt][nt], 0, 0, 0);
            acc[kt][nt] = __builtin_amdgcn_mfma_f32_32x32x16_f16(
                Al[kt], Bh[nt], acc[kt][nt], 0, 0, 0);
          }
      }
    }

#pragma unroll
    for (int i = 0; i < 8; ++i) {
      float n = nacc[i];
      n += __shfl_xor(n, 1, 64);
      n += __shfl_xor(n, 2, 64);
      n += __shfl_xor(n, 4, 64);
      if ((t & 7) == 0) nrm[(t >> 3) + 32 * i] = n;
    }
    __syncthreads();

#pragma unroll
    for (int kt = 0; kt < 2; ++kt) {
      const int kmb = w * 64 + kt * 32 + 4 * lhi;
#pragma unroll
      for (int r = 0; r < 16; ++r) {
        const int km = kmb + (r & 3) + 8 * (r >> 2);
        const float nk = nrm[km];
        const int kg = kbase + km;
#pragma unroll
        for (int nt = 0; nt < 2; ++nt) {
          const float d = fmaf(-2.0f, acc[kt][nt][r], nk);
          if (d < best[nt]) { best2[nt] = best[nt]; best[nt] = d; bidx[nt] = kg; }
          else best2[nt] = fminf(best2[nt], d);
        }
      }
    }
  }

#pragma unroll
  for (int nt = 0; nt < 2; ++nt) {
    float b = best[nt], b2 = best2[nt];
    int bi = bidx[nt];
    const float ob  = __shfl_xor(b, 32, 64);
    const float ob2 = __shfl_xor(b2, 32, 64);
    const int   obi = __shfl_xor(bi, 32, 64);
    const float nb2 = fminf(fminf(b2, ob2), fmaxf(b, ob));
    if (ob < b || (ob == b && obi < bi)) { b = ob; bi = obi; }
    if (lhi == 0) {
      const int row = nt * 32 + l31;
      sbest[row][w] = b; sbest2[row][w] = nb2; sbidx[row][w] = bi;
    }
  }
  __syncthreads();

  if (t < MROWS_FB) {
    float b = sbest[t][0], b2 = sbest2[t][0];
    int bi = sbidx[t][0];
#pragma unroll
    for (int ww = 1; ww < 4; ++ww) {
      const float cb = sbest[t][ww], cb2 = sbest2[t][ww];
      const int cbi = sbidx[t][ww];
      const float nb2 = fminf(fminf(b2, cb2), fmaxf(b, cb));
      if (cb < b || (cb == b && cbi < bi)) { b = cb; bi = cbi; }
      b2 = nb2;
    }
    sres[t] = bi;
    sflag[t] = (b2 - b < TAU) ? 1 : 0;
  }
  __syncthreads();

  float* xrw = (float*)&xs[0][0][0][0];
  for (int r = 0; r < MROWS_FB; ++r) {
    if (sflag[r]) {
      __syncthreads();
      for (int i = t; i < DIM / 4; i += 256)
        ((float4*)xrw)[i] = *(const float4*)(x + (row0 + r) * DIM + 4 * i);
      __syncthreads();
      float bd = INFINITY; int bk = NCENT;
      for (int i = 0; i < NCENT / 256; ++i) {
        const int k = t + 256 * i;
        const float4* crow = (const float4*)(cent + (size_t)k * DIM);
        float a0 = 0.f, a1 = 0.f, a2 = 0.f, a3 = 0.f;
        float n0 = 0.f, n1 = 0.f, n2 = 0.f, n3 = 0.f;
#pragma unroll 8
        for (int j = 0; j < DIM / 4; ++j) {
          const float4 cv = crow[j];
          const float4 xv = ((const float4*)xrw)[j];
          a0 = fmaf(cv.x, xv.x, a0); n0 = fmaf(cv.x, cv.x, n0);
          a1 = fmaf(cv.y, xv.y, a1); n1 = fmaf(cv.y, cv.y, n1);
          a2 = fmaf(cv.z, xv.z, a2); n2 = fmaf(cv.z, cv.z, n2);
          a3 = fmaf(cv.w, xv.w, a3); n3 = fmaf(cv.w, cv.w, n3);
        }
        const float d = fmaf(-2.f, (a0 + a1) + (a2 + a3), (n0 + n1) + (n2 + n3));
        if (d < bd || (d == bd && k < bk)) { bd = d; bk = k; }
      }
#pragma unroll
      for (int off = 32; off > 0; off >>= 1) {
        const float od = __shfl_down(bd, off, 64);
        const int   ok = __shfl_down(bk, off, 64);
        if (od < bd || (od == bd && ok < bk)) { bd = od; bk = ok; }
      }
      if (lane == 0) { p2d[w] = bd; p2k[w] = bk; }
      __syncthreads();
      if (t == 0) {
        float fd = p2d[0]; int fk = p2k[0];
#pragma unroll
        for (int ww = 1; ww < 4; ++ww) {
          if (p2d[ww] < fd || (p2d[ww] == fd && p2k[ww] < fk)) {
            fd = p2d[ww]; fk = p2k[ww];
          }
        }
        sres[r] = fk;
      }
      __syncthreads();
    }
  }
  __syncthreads();

  if (t < MROWS_FB) out[row0 + t] = sres[t];
}

extern "C" void kernel_launch(void* const* d_in, const int* in_sizes, int n_in,
                              void* d_out, int out_size, void* d_ws, size_t ws_size,
                              hipStream_t stream) {
  const float* x    = (const float*)d_in[0];   // [16,2000,1024] fp32
  const float* cent = (const float*)d_in[1];   // [2048,1024] fp32
  int* out = (int*)d_out;                      // 32000 int32 indices

  const size_t g_bytes = (size_t)NCENT * DIM * 2 * sizeof(_Float16);  // 8 MB
  const size_t need    = g_bytes + (size_t)NCENT * sizeof(float);
  if (d_ws != nullptr && ws_size >= need) {
    _Float16* G   = (_Float16*)d_ws;
    float* nrm_g  = (float*)((char*)d_ws + g_bytes);
    hipLaunchKernelGGL(kmeans_prep_kernel, dim3(NCENT), dim3(256), 0, stream,
                       cent, G, nrm_g);
    hipLaunchKernelGGL(kmeans_main_kernel, dim3(N_ROWS / MROWS), dim3(NTHR), 0,
                       stream, x, G, nrm_g, cent, out);
  } else {
    hipLaunchKernelGGL(kmeans_mfma_fallback, dim3(N_ROWS / MROWS_FB), dim3(256), 0,
                       stream, x, cent, out);
  }
}

// Round 8
// 1160.413 us; speedup vs baseline: 1.0551x; 1.0551x over previous
//
#include <hip/hip_runtime.h>
#include <math.h>

// Problem constants (B=16, T=2000, E=1024, K=2048)
#define N_ROWS 32000
#define DIM    1024
#define NCENT  2048
#define MROWS  128           // x rows per block (main kernel)
#define NKP    512           // centroids per k-pass (two 256-k G tiles per chunk)
#define NPASS  (NCENT / NKP) // 4
#define KE     16            // e per staged chunk
#define NCHUNK (DIM / KE)    // 64 chunks per pass
#define NTOT   (NPASS * NCHUNK)  // 256 flattened chunk iterations
#define NTHR   512           // 8 waves: each owns 64 centroids x 128 rows
#define TAU    0.015625f     // rescore margin (1/64, ~60 sigma of f16-split error)
// fallback-kernel constants
#define MROWS_FB 64
#define CS_KK  257
#define XS_KK  65

typedef _Float16 half4v __attribute__((ext_vector_type(4)));
typedef _Float16 half8v __attribute__((ext_vector_type(8)));
typedef float    floatx16 __attribute__((ext_vector_type(16)));

// Split a float4 into hi/lo f16 halves (RNE).
__device__ __forceinline__ void split4_f16(const float4 v, half4v& h, half4v& l) {
  const float f[4] = {v.x, v.y, v.z, v.w};
#pragma unroll
  for (int c = 0; c < 4; ++c) {
    const _Float16 hh = (_Float16)f[c];
    h[c] = hh;
    l[c] = (_Float16)(f[c] - (float)hh);
  }
}

// 16B global -> LDS DMA (wave-uniform LDS base + lane*16; our dest is linear in t).
__device__ __forceinline__ void gload_lds16(const _Float16* g, _Float16* l) {
  __builtin_amdgcn_global_load_lds(
      (const __attribute__((address_space(1))) void*)g,
      (__attribute__((address_space(3))) void*)l, 16, 0, 0);
}

// ---------------------------------------------------------------------------
// Pre-pass (UNCHANGED layout): split centroids once into the MFMA A-frag
// layout, tile-contiguous per (256-k group, chunk); exact fp32 norms once.
// G layout: tile g = (q*64+ec) = 8192 halfs (16 KB) for 256-k group q;
// within tile: idx = ((part*2+esub)*256 + kk)*8 + j  (part 0=hi 1=lo,
// esub=(e%16)>>3, kk=k%256, j=e%8). A-frag read = 8 contiguous f16 per lane.
// ---------------------------------------------------------------------------
__global__ void __launch_bounds__(256) kmeans_prep_kernel(
    const float* __restrict__ cent, _Float16* __restrict__ G,
    float* __restrict__ nrm_g) {
  const int k = blockIdx.x;       // centroid id
  const int t = threadIdx.x;      // owns float4 at e = 4t
  const float4 v = *(const float4*)(cent + (size_t)k * DIM + 4 * t);
  half4v h, l;
  split4_f16(v, h, l);
  const int e0 = 4 * t;
  const int p = k >> 8, kk = k & 255;
  const int ec = e0 >> 4, esub = (e0 >> 3) & 1, j = e0 & 7;  // j in {0,4}
  _Float16* tile = G + ((size_t)(p * NCHUNK + ec) << 13);
  *(half4v*)&tile[((0 * 2 + esub) * 256 + kk) * 8 + j] = h;
  *(half4v*)&tile[((1 * 2 + esub) * 256 + kk) * 8 + j] = l;

  float n = fmaf(v.x, v.x, fmaf(v.y, v.y, fmaf(v.z, v.z, v.w * v.w)));
  n += __shfl_xor(n, 1, 64);
  n += __shfl_xor(n, 2, 64);
  n += __shfl_xor(n, 4, 64);
  n += __shfl_xor(n, 8, 64);
  n += __shfl_xor(n, 16, 64);
  n += __shfl_xor(n, 32, 64);
  __shared__ float sn[4];
  if ((t & 63) == 0) sn[t >> 6] = n;
  __syncthreads();
  if (t == 0) nrm_g[k] = (sn[0] + sn[1]) + (sn[2] + sn[3]);
}

// ---------------------------------------------------------------------------
// Main kernel: 128 rows/block, 8 waves, NKP=512, 250 blocks (1/CU; per-CU
// staged bytes = G 8MB + x 2MB). DEPTH-2 staging pipeline (the round-7 fix):
// triple-buffered cs/xs; iteration i issues stage(i+2); the tail x(i+2)
// register-consume (x issued BEFORE the 4 g-DMAs -> it is older) forces
// exactly vmcnt(4): chunk i+1's DMAs drained, chunk i+2's 4 DMAs stay IN
// FLIGHT ACROSS THE BARRIER -> each DMA gets ~2 intervals of service.
// Norms preloaded to LDS so pass epilogues issue no VMEM (no pipe drain).
// mfma_f32_32x32x16_f16: A[m=k][e], B[e][n=row],
// D: col(n)=lane&31, row(m)=(reg&3)+8*(reg>>2)+4*(lane>>5).
// ---------------------------------------------------------------------------
__global__ void __launch_bounds__(512, 2) kmeans_main_kernel(
    const float* __restrict__ x, const _Float16* __restrict__ G,
    const float* __restrict__ nrm_g, const float* __restrict__ cent,
    int* __restrict__ out) {
  __shared__ __align__(16) _Float16 cs[3][16384];      // 96 KB, 3-deep
  __shared__ __align__(16) _Float16 xs[3][4][128][8];  // 24 KB, 3-deep
  __shared__ float nrm_all[NCENT];                     //  8 KB
  __shared__ float sbest[MROWS][8];
  __shared__ float sbest2[MROWS][8];
  __shared__ int   sbidx[MROWS][8];
  __shared__ int   sres[MROWS];
  __shared__ int   sflag[MROWS];
  __shared__ float p2d[8];
  __shared__ int   p2k[8];

  const int t    = threadIdx.x;
  const int lane = t & 63;
  const int w    = t >> 6;      // wave 0..7 -> 64-centroid slice within pass
  const int l31  = lane & 31;
  const int lhi  = lane >> 5;   // 0/1
  const size_t row0 = (size_t)blockIdx.x * MROWS;

  // x staging geometry: 128 rows x 16 e = 512 float4 = 1 per thread.
  const int xrow  = t >> 2, xe4 = t & 3;
  const int xesub = xe4 >> 1, xj = (xe4 & 1) * 4;
  const float* xsrc = x + (row0 + xrow) * DIM + 4 * xe4;

  float best[4]  = {INFINITY, INFINITY, INFINITY, INFINITY};
  float best2[4] = {INFINITY, INFINITY, INFINITY, INFINITY};
  int   bidx[4]  = {0, 0, 0, 0};

  floatx16 acc[2][4] = {};   // [kt][nt]
  const floatx16 zacc = {};

  auto stage_g = [&](int g2, int b) {
    // chunk g2 in [0,NTOT): pass p=g2>>6 uses 256-k groups 2p,2p+1; ec=g2&63.
    const _Float16* gt =
        G + ((size_t)(((g2 >> 6) * 2) * NCHUNK + (g2 & 63)) << 13);
#pragma unroll
    for (int ii = 0; ii < 2; ++ii) {
      gload_lds16(gt + t * 8 + ii * 4096, &cs[b][t * 8 + ii * 4096]);
      gload_lds16(gt + (64 << 13) + t * 8 + ii * 4096,
                  &cs[b][8192 + t * 8 + ii * 4096]);
    }
  };
  auto store_x = [&](const float4 v, int b) {
    half4v h, l;
    split4_f16(v, h, l);
    *(half4v*)&xs[b][0 * 2 + xesub][xrow][xj] = h;
    *(half4v*)&xs[b][1 * 2 + xesub][xrow][xj] = l;
  };
  auto do_mfma = [&](int b) {
    const _Float16* cb = &cs[b][0];
    const _Float16* xb = &xs[b][0][0][0];
    half8v Ah[2], Al[2];
#pragma unroll
    for (int kt = 0; kt < 2; ++kt) {
      const int ks = w * 64 + kt * 32 + l31;     // k within pass [0,512)
      const int toff = (ks >> 8) * 8192;         // which 16-KB G tile half
      const int kk = ks & 255;
      Ah[kt] = *(const half8v*)&cb[toff + (lhi * 256 + kk) * 8];        // hi
      Al[kt] = *(const half8v*)&cb[toff + ((2 + lhi) * 256 + kk) * 8];  // lo
    }
    __builtin_amdgcn_s_setprio(1);
#pragma unroll
    for (int nt = 0; nt < 4; ++nt) {
      const int rr = nt * 32 + l31;
      const half8v Bh = *(const half8v*)&xb[(lhi * 128 + rr) * 8];
      const half8v Bl = *(const half8v*)&xb[((2 + lhi) * 128 + rr) * 8];
#pragma unroll
      for (int kt = 0; kt < 2; ++kt) {
        acc[kt][nt] = __builtin_amdgcn_mfma_f32_32x32x16_f16(Ah[kt], Bh, acc[kt][nt], 0, 0, 0);
        acc[kt][nt] = __builtin_amdgcn_mfma_f32_32x32x16_f16(Ah[kt], Bl, acc[kt][nt], 0, 0, 0);
        acc[kt][nt] = __builtin_amdgcn_mfma_f32_32x32x16_f16(Al[kt], Bh, acc[kt][nt], 0, 0, 0);
      }
    }
    __builtin_amdgcn_s_setprio(0);
  };

  // Prologue: norms -> LDS; x chunks 0,1; g chunks 0,1; full drain once.
  for (int idx = t; idx < NCENT; idx += NTHR) nrm_all[idx] = nrm_g[idx];
  store_x(*(const float4*)(xsrc), 0);
  store_x(*(const float4*)(xsrc + KE), 1);
  stage_g(0, 0);
  stage_g(1, 1);
  __syncthreads();

  for (int i = 0; i < NTOT; ++i) {
    const int bc = i % 3;
    const bool hx = (i + 2 < NTOT);
    float4 xn;
    if (hx) xn = *(const float4*)(xsrc + (size_t)((i + 2) & 63) * KE);
    __builtin_amdgcn_sched_barrier(0);  // pin x-load BEFORE the g-DMA issues
    if (hx) stage_g(i + 2, (i + 2) % 3);

    do_mfma(bc);

    if ((i & 63) == 63) {
      // Pass epilogue (LDS + registers only -- no VMEM, pipeline stays full):
      // d = nrm[k] - 2*dot; near-ties land in tau-flag -> exact rescore.
      const int kbase = (i >> 6) * NKP;
      const int kmb = w * 64 + 4 * lhi;
#pragma unroll
      for (int kt = 0; kt < 2; ++kt) {
#pragma unroll
        for (int r = 0; r < 16; ++r) {
          const int km = kmb + kt * 32 + (r & 3) + 8 * (r >> 2);
          const int kg = kbase + km;
          const float nk = nrm_all[kg];
#pragma unroll
          for (int nt = 0; nt < 4; ++nt) {
            const float d = fmaf(-2.0f, acc[kt][nt][r], nk);
            if (d < best[nt]) { best2[nt] = best[nt]; best[nt] = d; bidx[nt] = kg; }
            else best2[nt] = fminf(best2[nt], d);
          }
        }
      }
#pragma unroll
      for (int kt = 0; kt < 2; ++kt)
#pragma unroll
        for (int nt = 0; nt < 4; ++nt) acc[kt][nt] = zacc;
    }

    // Tail: consuming xn forces vmcnt(4) (x older than this chunk's 4 g-DMAs,
    // newer than chunk i+1's) -> i+1 resident, i+2's DMAs live across barrier.
    if (hx) {
      store_x(xn, (i + 2) % 3);
    } else {
      asm volatile("s_waitcnt vmcnt(0)" ::: "memory");  // tail iterations
    }
    asm volatile("s_waitcnt lgkmcnt(0)" ::: "memory");
    __builtin_amdgcn_s_barrier();
    __builtin_amdgcn_sched_barrier(0);  // no ds_read hoisting above barrier
  }

  // Merge lane halves (l, l^32) then write per-wave row candidates.
#pragma unroll
  for (int nt = 0; nt < 4; ++nt) {
    float b = best[nt], b2 = best2[nt];
    int bi = bidx[nt];
    const float ob  = __shfl_xor(b, 32, 64);
    const float ob2 = __shfl_xor(b2, 32, 64);
    const int   obi = __shfl_xor(bi, 32, 64);
    const float nb2 = fminf(fminf(b2, ob2), fmaxf(b, ob));
    if (ob < b || (ob == b && obi < bi)) { b = ob; bi = obi; }
    if (lhi == 0) {
      const int row = nt * 32 + l31;
      sbest[row][w] = b; sbest2[row][w] = nb2; sbidx[row][w] = bi;
    }
  }
  __syncthreads();

  if (t < MROWS) {
    float b = sbest[t][0], b2 = sbest2[t][0];
    int bi = sbidx[t][0];
#pragma unroll
    for (int ww = 1; ww < 8; ++ww) {
      const float cb = sbest[t][ww], cb2 = sbest2[t][ww];
      const int cbi = sbidx[t][ww];
      const float nb2 = fminf(fminf(b2, cb2), fmaxf(b, cb));
      if (cb < b || (cb == b && cbi < bi)) { b = cb; bi = cbi; }
      b2 = nb2;
    }
    sres[t] = bi;
    sflag[t] = (b2 - b < TAU) ? 1 : 0;
  }
  __syncthreads();

  // Phase 2: exact fp32 rescore of flagged rows (expected ~0-1 per ~25 blocks).
  float* xrw = (float*)&xs[0][0][0][0];  // 4 KB fp32 scratch, reuses xs
  for (int r = 0; r < MROWS; ++r) {
    if (sflag[r]) {               // uniform branch (same LDS word for all threads)
      __syncthreads();
      for (int i = t; i < DIM / 4; i += NTHR)
        ((float4*)xrw)[i] = *(const float4*)(x + (row0 + r) * DIM + 4 * i);
      __syncthreads();
      float bd = INFINITY; int bk = NCENT;
      for (int i = 0; i < NCENT / NTHR; ++i) {
        const int k = t + NTHR * i;
        const float4* crow = (const float4*)(cent + (size_t)k * DIM);
        float a0 = 0.f, a1 = 0.f, a2 = 0.f, a3 = 0.f;
        float n0 = 0.f, n1 = 0.f, n2 = 0.f, n3 = 0.f;
#pragma unroll 8
        for (int j = 0; j < DIM / 4; ++j) {
          const float4 cv = crow[j];
          const float4 xv = ((const float4*)xrw)[j];
          a0 = fmaf(cv.x, xv.x, a0); n0 = fmaf(cv.x, cv.x, n0);
          a1 = fmaf(cv.y, xv.y, a1); n1 = fmaf(cv.y, cv.y, n1);
          a2 = fmaf(cv.z, xv.z, a2); n2 = fmaf(cv.z, cv.z, n2);
          a3 = fmaf(cv.w, xv.w, a3); n3 = fmaf(cv.w, cv.w, n3);
        }
        const float d = fmaf(-2.f, (a0 + a1) + (a2 + a3), (n0 + n1) + (n2 + n3));
        if (d < bd || (d == bd && k < bk)) { bd = d; bk = k; }
      }
#pragma unroll
      for (int off = 32; off > 0; off >>= 1) {
        const float od = __shfl_down(bd, off, 64);
        const int   ok = __shfl_down(bk, off, 64);
        if (od < bd || (od == bd && ok < bk)) { bd = od; bk = ok; }
      }
      if (lane == 0) { p2d[w] = bd; p2k[w] = bk; }
      __syncthreads();
      if (t == 0) {
        float fd = p2d[0]; int fk = p2k[0];
#pragma unroll
        for (int ww = 1; ww < 8; ++ww) {
          if (p2d[ww] < fd || (p2d[ww] == fd && p2k[ww] < fk)) {
            fd = p2d[ww]; fk = p2k[ww];
          }
        }
        sres[r] = fk;
      }
      __syncthreads();
    }
  }
  __syncthreads();

  if (t < MROWS) out[row0 + t] = sres[t];
}

// ---------------------------------------------------------------------------
// Fallback (verified, in-kernel split, 64 rows/block, KE=32) — used only if
// the workspace is too small for the pre-split centroid buffer.
// ---------------------------------------------------------------------------
__global__ void __launch_bounds__(256, 2) kmeans_mfma_fallback(
    const float* __restrict__ x, const float* __restrict__ cent,
    int* __restrict__ out) {
  __shared__ __align__(16) _Float16 cs[2][4][CS_KK][8];
  __shared__ __align__(16) _Float16 xs[2][4][XS_KK][8];
  __shared__ float nrm[256];
  __shared__ float sbest[MROWS_FB][4];
  __shared__ float sbest2[MROWS_FB][4];
  __shared__ int   sbidx[MROWS_FB][4];
  __shared__ int   sres[MROWS_FB];
  __shared__ int   sflag[MROWS_FB];
  __shared__ float p2d[4];
  __shared__ int   p2k[4];

  const int t    = threadIdx.x;
  const int lane = t & 63;
  const int w    = t >> 6;
  const int l31  = lane & 31;
  const int lhi  = lane >> 5;
  const size_t row0 = (size_t)blockIdx.x * MROWS_FB;

  float best[2]  = {INFINITY, INFINITY};
  float best2[2] = {INFINITY, INFINITY};
  int   bidx[2]  = {0, 0};

  for (int p = 0; p < 8; ++p) {
    const int kbase = p * 256;
    floatx16 acc[2][2] = {};
    float nacc[8] = {};

    for (int ec = 0; ec < 32; ++ec) {
      const int ebase = ec * 32;
      __syncthreads();
#pragma unroll
      for (int i = 0; i < 2; ++i) {
        const int idx = t + 256 * i;
        const int row = idx >> 3, e4 = idx & 7;
        const float4 v = *(const float4*)(x + (row0 + row) * DIM + ebase + 4 * e4);
        half4v h, l;
        split4_f16(v, h, l);
        *(half4v*)&xs[0][e4 >> 1][row][(e4 & 1) * 4] = h;
        *(half4v*)&xs[1][e4 >> 1][row][(e4 & 1) * 4] = l;
      }
#pragma unroll
      for (int i = 0; i < 8; ++i) {
        const int idx = t + 256 * i;
        const int kk = idx >> 3, e4 = idx & 7;
        const float4 v =
            *(const float4*)(cent + (size_t)(kbase + kk) * DIM + ebase + 4 * e4);
        nacc[i] = fmaf(v.x, v.x, nacc[i]); nacc[i] = fmaf(v.y, v.y, nacc[i]);
        nacc[i] = fmaf(v.z, v.z, nacc[i]); nacc[i] = fmaf(v.w, v.w, nacc[i]);
        half4v h, l;
        split4_f16(v, h, l);
        *(half4v*)&cs[0][e4 >> 1][kk][(e4 & 1) * 4] = h;
        *(half4v*)&cs[1][e4 >> 1][kk][(e4 & 1) * 4] = l;
      }
      __syncthreads();

#pragma unroll
      for (int es = 0; es < 2; ++es) {
        const int esub = es * 2 + lhi;
        half8v Ah[2], Al[2], Bh[2], Bl[2];
#pragma unroll
        for (int kt = 0; kt < 2; ++kt) {
          const int kk = w * 64 + kt * 32 + l31;
          Ah[kt] = *(const half8v*)&cs[0][esub][kk][0];
          Al[kt] = *(const half8v*)&cs[1][esub][kk][0];
        }
#pragma unroll
        for (int nt = 0; nt < 2; ++nt) {
          const int rr = nt * 32 + l31;
          Bh[nt] = *(const half8v*)&xs[0][esub][rr][0];
          Bl[nt] = *(const half8v*)&xs[1][esub][rr][0];
        }
#pragma unroll
        for (int kt = 0; kt < 2; ++kt)
#pragma unroll
          for (int nt = 0; nt < 2; ++nt) {
            acc[kt][nt] = __builtin_amdgcn_mfma_f32_32x32x16_f16(
                Ah[kt], Bh[nt], acc[kt][nt], 0, 0, 0);
            acc[kt][nt] = __builtin_amdgcn_mfma_f32_32x32x16_f16(
                Ah[kt], Bl[nt], acc[kt][nt], 0, 0, 0);
            acc[kt][nt] = __builtin_amdgcn_mfma_f32_32x32x16_f16(
                Al[kt], Bh[nt], acc[kt][nt], 0, 0, 0);
          }
      }
    }

#pragma unroll
    for (int i = 0; i < 8; ++i) {
      float n = nacc[i];
      n += __shfl_xor(n, 1, 64);
      n += __shfl_xor(n, 2, 64);
      n += __shfl_xor(n, 4, 64);
      if ((t & 7) == 0) nrm[(t >> 3) + 32 * i] = n;
    }
    __syncthreads();

#pragma unroll
    for (int kt = 0; kt < 2; ++kt) {
      const int kmb = w * 64 + kt * 32 + 4 * lhi;
#pragma unroll
      for (int r = 0; r < 16; ++r) {
        const int km = kmb + (r & 3) + 8 * (r >> 2);
        const float nk = nrm[km];
        const int kg = kbase + km;
#pragma unroll
        for (int nt = 0; nt < 2; ++nt) {
          const float d = fmaf(-2.0f, acc[kt][nt][r], nk);
          if (d < best[nt]) { best2[nt] = best[nt]; best[nt] = d; bidx[nt] = kg; }
          else best2[nt] = fminf(best2[nt], d);
        }
      }
    }
  }

#pragma unroll
  for (int nt = 0; nt < 2; ++nt) {
    float b = best[nt], b2 = best2[nt];
    int bi = bidx[nt];
    const float ob  = __shfl_xor(b, 32, 64);
    const float ob2 = __shfl_xor(b2, 32, 64);
    const int   obi = __shfl_xor(bi, 32, 64);
    const float nb2 = fminf(fminf(b2, ob2), fmaxf(b, ob));
    if (ob < b || (ob == b && obi < bi)) { b = ob; bi = obi; }
    if (lhi == 0) {
      const int row = nt * 32 + l31;
      sbest[row][w] = b; sbest2[row][w] = nb2; sbidx[row][w] = bi;
    }
  }
  __syncthreads();

  if (t < MROWS_FB) {
    float b = sbest[t][0], b2 = sbest2[t][0];
    int bi = sbidx[t][0];
#pragma unroll
    for (int ww = 1; ww < 4; ++ww) {
      const float cb = sbest[t][ww], cb2 = sbest2[t][ww];
      const int cbi = sbidx[t][ww];
      const float nb2 = fminf(fminf(b2, cb2), fmaxf(b, cb));
      if (cb < b || (cb == b && cbi < bi)) { b = cb; bi = cbi; }
      b2 = nb2;
    }
    sres[t] = bi;
    sflag[t] = (b2 - b < TAU) ? 1 : 0;
  }
  __syncthreads();

  float* xrw = (float*)&xs[0][0][0][0];
  for (int r = 0; r < MROWS_FB; ++r) {
    if (sflag[r]) {
      __syncthreads();
      for (int i = t; i < DIM / 4; i += 256)
        ((float4*)xrw)[i] = *(const float4*)(x + (row0 + r) * DIM + 4 * i);
      __syncthreads();
      float bd = INFINITY; int bk = NCENT;
      for (int i = 0; i < NCENT / 256; ++i) {
        const int k = t + 256 * i;
        const float4* crow = (const float4*)(cent + (size_t)k * DIM);
        float a0 = 0.f, a1 = 0.f, a2 = 0.f, a3 = 0.f;
        float n0 = 0.f, n1 = 0.f, n2 = 0.f, n3 = 0.f;
#pragma unroll 8
        for (int j = 0; j < DIM / 4; ++j) {
          const float4 cv = crow[j];
          const float4 xv = ((const float4*)xrw)[j];
          a0 = fmaf(cv.x, xv.x, a0); n0 = fmaf(cv.x, cv.x, n0);
          a1 = fmaf(cv.y, xv.y, a1); n1 = fmaf(cv.y, cv.y, n1);
          a2 = fmaf(cv.z, xv.z, a2); n2 = fmaf(cv.z, cv.z, n2);
          a3 = fmaf(cv.w, xv.w, a3); n3 = fmaf(cv.w, cv.w, n3);
        }
        const float d = fmaf(-2.f, (a0 + a1) + (a2 + a3), (n0 + n1) + (n2 + n3));
        if (d < bd || (d == bd && k < bk)) { bd = d; bk = k; }
      }
#pragma unroll
      for (int off = 32; off > 0; off >>= 1) {
        const float od = __shfl_down(bd, off, 64);
        const int   ok = __shfl_down(bk, off, 64);
        if (od < bd || (od == bd && ok < bk)) { bd = od; bk = ok; }
      }
      if (lane == 0) { p2d[w] = bd; p2k[w] = bk; }
      __syncthreads();
      if (t == 0) {
        float fd = p2d[0]; int fk = p2k[0];
#pragma unroll
        for (int ww = 1; ww < 4; ++ww) {
          if (p2d[ww] < fd || (p2d[ww] == fd && p2k[ww] < fk)) {
            fd = p2d[ww]; fk = p2k[ww];
          }
        }
        sres[r] = fk;
      }
      __syncthreads();
    }
  }
  __syncthreads();

  if (t < MROWS_FB) out[row0 + t] = sres[t];
}

extern "C" void kernel_launch(void* const* d_in, const int* in_sizes, int n_in,
                              void* d_out, int out_size, void* d_ws, size_t ws_size,
                              hipStream_t stream) {
  const float* x    = (const float*)d_in[0];   // [16,2000,1024] fp32
  const float* cent = (const float*)d_in[1];   // [2048,1024] fp32
  int* out = (int*)d_out;                      // 32000 int32 indices

  const size_t g_bytes = (size_t)NCENT * DIM * 2 * sizeof(_Float16);  // 8 MB
  const size_t need    = g_bytes + (size_t)NCENT * sizeof(float);
  if (d_ws != nullptr && ws_size >= need) {
    _Float16* G   = (_Float16*)d_ws;
    float* nrm_g  = (float*)((char*)d_ws + g_bytes);
    hipLaunchKernelGGL(kmeans_prep_kernel, dim3(NCENT), dim3(256), 0, stream,
                       cent, G, nrm_g);
    hipLaunchKernelGGL(kmeans_main_kernel, dim3(N_ROWS / MROWS), dim3(NTHR), 0,
                       stream, x, G, nrm_g, cent, out);
  } else {
    hipLaunchKernelGGL(kmeans_mfma_fallback, dim3(N_ROWS / MROWS_FB), dim3(256), 0,
                       stream, x, cent, out);
  }
}

// Round 9
// 787.010 us; speedup vs baseline: 1.5557x; 1.4745x over previous
//
#include <hip/hip_runtime.h>
#include <math.h>

// Problem constants (B=16, T=2000, E=1024, K=2048)
#define N_ROWS 32000
#define DIM    1024
#define NCENT  2048
#define MROWS  128           // x rows per block (main kernel)
#define KHALF  1024          // centroids per block (split-K across 2 blocks)
#define NKP    256           // centroids per k-pass
#define NPASS  (KHALF / NKP) // 4
#define KE     16            // e per staged chunk
#define NCHUNK (DIM / KE)    // 64 chunks per pass
#define NTHR   512           // 8 waves: each owns 32 centroids x 128 rows
#define TAU    0.015625f     // rescore margin (1/64, ~60 sigma of f16-split error)
// fallback-kernel constants
#define MROWS_FB 64
#define CS_KK  257
#define XS_KK  65

typedef _Float16 half4v __attribute__((ext_vector_type(4)));
typedef _Float16 half8v __attribute__((ext_vector_type(8)));
typedef float    floatx16 __attribute__((ext_vector_type(16)));

// Split a float4 into hi/lo f16 halves (RNE).
__device__ __forceinline__ void split4_f16(const float4 v, half4v& h, half4v& l) {
  const float f[4] = {v.x, v.y, v.z, v.w};
#pragma unroll
  for (int c = 0; c < 4; ++c) {
    const _Float16 hh = (_Float16)f[c];
    h[c] = hh;
    l[c] = (_Float16)(f[c] - (float)hh);
  }
}

// 16B global -> LDS DMA (wave-uniform LDS base + lane*16; our dest is linear in t).
__device__ __forceinline__ void gload_lds16(const _Float16* g, _Float16* l) {
  __builtin_amdgcn_global_load_lds(
      (const __attribute__((address_space(1))) void*)g,
      (__attribute__((address_space(3))) void*)l, 16, 0, 0);
}

// ---------------------------------------------------------------------------
// Pre-pass (UNCHANGED G layout): split centroids once into the MFMA A-frag
// layout, tile-contiguous per (256-k group, chunk); exact fp32 norms once.
// Also zeroes the rescore counter (runs before merge in-stream).
// G layout: tile g = (q*64+ec) = 8192 halfs (16 KB) for 256-k group q;
// within tile: idx = ((part*2+esub)*256 + kk)*8 + j  (part 0=hi 1=lo,
// esub=(e%16)>>3, kk=k%256, j=e%8). A-frag read = 8 contiguous f16 per lane.
// ---------------------------------------------------------------------------
__global__ void __launch_bounds__(256) kmeans_prep_kernel(
    const float* __restrict__ cent, _Float16* __restrict__ G,
    float* __restrict__ nrm_g, int* __restrict__ cnt) {
  const int k = blockIdx.x;       // centroid id
  const int t = threadIdx.x;      // owns float4 at e = 4t
  if (k == 0 && t == 0) *cnt = 0;
  const float4 v = *(const float4*)(cent + (size_t)k * DIM + 4 * t);
  half4v h, l;
  split4_f16(v, h, l);
  const int e0 = 4 * t;
  const int p = k >> 8, kk = k & 255;
  const int ec = e0 >> 4, esub = (e0 >> 3) & 1, j = e0 & 7;  // j in {0,4}
  _Float16* tile = G + ((size_t)(p * NCHUNK + ec) << 13);
  *(half4v*)&tile[((0 * 2 + esub) * 256 + kk) * 8 + j] = h;
  *(half4v*)&tile[((1 * 2 + esub) * 256 + kk) * 8 + j] = l;

  float n = fmaf(v.x, v.x, fmaf(v.y, v.y, fmaf(v.z, v.z, v.w * v.w)));
  n += __shfl_xor(n, 1, 64);
  n += __shfl_xor(n, 2, 64);
  n += __shfl_xor(n, 4, 64);
  n += __shfl_xor(n, 8, 64);
  n += __shfl_xor(n, 16, 64);
  n += __shfl_xor(n, 32, 64);
  __shared__ float sn[4];
  if ((t & 63) == 0) sn[t >> 6] = n;
  __syncthreads();
  if (t == 0) nrm_g[k] = (sn[0] + sn[1]) + (sn[2] + sn[3]);
}

// ---------------------------------------------------------------------------
// Main kernel (SPLIT-K): grid 500 = 250 row-groups x 2 centroid-halves.
// Each block: 128 rows x 1024 centroids -> stages only 4 MB of G (+2 MB x)
// instead of 8+1 (the measured ~10 GB/s/block staging law makes bytes/block
// the wall time). r6's verified schedule kept verbatim: double-buffered
// KE=16 chunks, DMA+x-load at head, x split+store write-late, one barrier
// per chunk. Per wave: 32 centroids x 128 rows (acc 4x f32x16 = 64 VGPR).
// Block writes per-row {best, best2, idx} candidates; merge kernel combines.
// mfma_f32_32x32x16_f16: A[m=k][e], B[e][n=row],
// D: col(n)=lane&31, row(m)=(reg&3)+8*(reg>>2)+4*(lane>>5).
// ---------------------------------------------------------------------------
__global__ void __launch_bounds__(512, 4) kmeans_main_kernel(
    const float* __restrict__ x, const _Float16* __restrict__ G,
    const float* __restrict__ nrm_g,
    float* __restrict__ candb, float* __restrict__ candb2,
    int* __restrict__ candi) {
  __shared__ __align__(16) _Float16 cs[2][8192];       // 32 KB dbuf
  __shared__ __align__(16) _Float16 xs[2][4][128][8];  // 16 KB dbuf
  __shared__ float sbest[MROWS][8];
  __shared__ float sbest2[MROWS][8];
  __shared__ int   sbidx[MROWS][8];

  const int t    = threadIdx.x;
  const int lane = t & 63;
  const int w    = t >> 6;      // wave 0..7 -> 32-centroid slice within pass
  const int l31  = lane & 31;
  const int lhi  = lane >> 5;   // 0/1
  const int rowgrp = blockIdx.x >> 1;
  const int half   = blockIdx.x & 1;
  const size_t row0 = (size_t)rowgrp * MROWS;
  const int kbase0 = half * KHALF;

  // x staging geometry: 128 rows x 16 e = 512 float4 = 1 per thread.
  const int xrow  = t >> 2, xe4 = t & 3;
  const int xesub = xe4 >> 1, xj = (xe4 & 1) * 4;
  const float* xsrc = x + (row0 + xrow) * DIM + 4 * xe4;

  float best[4]  = {INFINITY, INFINITY, INFINITY, INFINITY};
  float best2[4] = {INFINITY, INFINITY, INFINITY, INFINITY};
  int   bidx[4]  = {0, 0, 0, 0};

  for (int p = 0; p < NPASS; ++p) {
    const int q = half * NPASS + p;          // 256-k group id in G
    const int kbase = kbase0 + p * NKP;
    floatx16 acc[4] = {};   // [nt]

    auto do_mfma = [&](int b) {
      const _Float16* cb = &cs[b][0];
      const _Float16* xb = &xs[b][0][0][0];
      const int kk = w * 32 + l31;
      const half8v Ah = *(const half8v*)&cb[(lhi * 256 + kk) * 8];        // hi
      const half8v Al = *(const half8v*)&cb[((2 + lhi) * 256 + kk) * 8];  // lo
      __builtin_amdgcn_s_setprio(1);
#pragma unroll
      for (int nt = 0; nt < 4; ++nt) {
        const int rr = nt * 32 + l31;
        const half8v Bh = *(const half8v*)&xb[(lhi * 128 + rr) * 8];
        const half8v Bl = *(const half8v*)&xb[((2 + lhi) * 128 + rr) * 8];
        acc[nt] = __builtin_amdgcn_mfma_f32_32x32x16_f16(Ah, Bh, acc[nt], 0, 0, 0);
        acc[nt] = __builtin_amdgcn_mfma_f32_32x32x16_f16(Ah, Bl, acc[nt], 0, 0, 0);
        acc[nt] = __builtin_amdgcn_mfma_f32_32x32x16_f16(Al, Bh, acc[nt], 0, 0, 0);
      }
      __builtin_amdgcn_s_setprio(0);
    };

    __syncthreads();  // previous pass fully done before buffer overwrite

    // Prologue: stage chunk 0 into buffer 0.
    {
      const _Float16* gt = G + ((size_t)(q * NCHUNK) << 13);
#pragma unroll
      for (int i = 0; i < 2; ++i)
        gload_lds16(gt + t * 8 + i * 4096, &cs[0][t * 8 + i * 4096]);
      const float4 xv = *(const float4*)(xsrc);
      half4v h, l;
      split4_f16(xv, h, l);
      *(half4v*)&xs[0][0 * 2 + xesub][xrow][xj] = h;
      *(half4v*)&xs[0][1 * 2 + xesub][xrow][xj] = l;
    }
    __syncthreads();  // chunk 0 resident

    int cur = 0;
    for (int ec = 0; ec < NCHUNK - 1; ++ec) {
      const int nb = cur ^ 1;
      // Issue next chunk's loads FIRST (latency hides under the MFMAs).
      const _Float16* gt = G + ((size_t)(q * NCHUNK + ec + 1) << 13);
#pragma unroll
      for (int i = 0; i < 2; ++i)
        gload_lds16(gt + t * 8 + i * 4096, &cs[nb][t * 8 + i * 4096]);
      const float4 xn = *(const float4*)(xsrc + (ec + 1) * KE);

      do_mfma(cur);

      // Write-late: split+store x for next chunk after compute.
      {
        half4v h, l;
        split4_f16(xn, h, l);
        *(half4v*)&xs[nb][0 * 2 + xesub][xrow][xj] = h;
        *(half4v*)&xs[nb][1 * 2 + xesub][xrow][xj] = l;
      }
      __syncthreads();  // drains gload_lds (vmcnt) + ds writes; next chunk ready
      cur = nb;
    }
    do_mfma(cur);  // tail chunk (no prefetch)

    // Pass epilogue: d = nrm[k] - 2*dot; norms from global (L2-resident).
    {
      const int kmb = w * 32 + 4 * lhi;
#pragma unroll
      for (int r = 0; r < 16; ++r) {
        const int km = kmb + (r & 3) + 8 * (r >> 2);
        const int kg = kbase + km;
        const float nk = nrm_g[kg];
#pragma unroll
        for (int nt = 0; nt < 4; ++nt) {
          const float d = fmaf(-2.0f, acc[nt][r], nk);
          if (d < best[nt]) { best2[nt] = best[nt]; best[nt] = d; bidx[nt] = kg; }
          else best2[nt] = fminf(best2[nt], d);
        }
      }
    }
  }

  // Merge lane halves (l, l^32) then write per-wave row candidates.
#pragma unroll
  for (int nt = 0; nt < 4; ++nt) {
    float b = best[nt], b2 = best2[nt];
    int bi = bidx[nt];
    const float ob  = __shfl_xor(b, 32, 64);
    const float ob2 = __shfl_xor(b2, 32, 64);
    const int   obi = __shfl_xor(bi, 32, 64);
    const float nb2 = fminf(fminf(b2, ob2), fmaxf(b, ob));
    if (ob < b || (ob == b && obi < bi)) { b = ob; bi = obi; }
    if (lhi == 0) {
      const int row = nt * 32 + l31;
      sbest[row][w] = b; sbest2[row][w] = nb2; sbidx[row][w] = bi;
    }
  }
  __syncthreads();

  if (t < MROWS) {
    float b = sbest[t][0], b2 = sbest2[t][0];
    int bi = sbidx[t][0];
#pragma unroll
    for (int ww = 1; ww < 8; ++ww) {
      const float cb = sbest[t][ww], cb2 = sbest2[t][ww];
      const int cbi = sbidx[t][ww];
      const float nb2 = fminf(fminf(b2, cb2), fmaxf(b, cb));
      if (cb < b || (cb == b && cbi < bi)) { b = cb; bi = cbi; }
      b2 = nb2;
    }
    const size_t ci = (row0 + t) * 2 + half;
    candb[ci] = b; candb2[ci] = b2; candi[ci] = bi;
  }
}

// ---------------------------------------------------------------------------
// Merge kernel: combine the two centroid-half candidates per row; exact
// union second-best = min(winner's 2nd, loser's best). Same TAU flag as
// before; flagged rows appended to rescore list.
// ---------------------------------------------------------------------------
__global__ void __launch_bounds__(256) kmeans_merge_kernel(
    const float* __restrict__ candb, const float* __restrict__ candb2,
    const int* __restrict__ candi, int* __restrict__ out,
    int* __restrict__ cnt, int* __restrict__ list) {
  const int row = blockIdx.x * 256 + threadIdx.x;
  if (row >= N_ROWS) return;
  const float b0 = candb[row * 2],     b20 = candb2[row * 2];
  const float b1 = candb[row * 2 + 1], b21 = candb2[row * 2 + 1];
  const int   i0 = candi[row * 2],     i1 = candi[row * 2 + 1];
  float bm, b2m; int im;
  if (b1 < b0) { bm = b1; im = i1; b2m = fminf(b21, b0); }
  else         { bm = b0; im = i0; b2m = fminf(b20, b1); }  // tie -> half0 (lower idx)
  out[row] = im;
  if (b2m - bm < TAU) {
    const int s = atomicAdd(cnt, 1);
    list[s] = row;
  }
}

// ---------------------------------------------------------------------------
// Rescore kernel: exact fp32 argmin for flagged rows (expected ~0 rows).
// Fixed grid of 64 blocks striding the list; no host readback needed.
// ---------------------------------------------------------------------------
__global__ void __launch_bounds__(256) kmeans_rescore_kernel(
    const float* __restrict__ x, const float* __restrict__ cent,
    int* __restrict__ out, const int* __restrict__ cnt,
    const int* __restrict__ list) {
  __shared__ float xrow[DIM];
  __shared__ float p2d[4];
  __shared__ int   p2k[4];
  const int t = threadIdx.x;
  const int lane = t & 63;
  const int w = t >> 6;
  const int n = *cnt;
  for (int ii = blockIdx.x; ii < n; ii += 64) {
    const int row = list[ii];
    __syncthreads();
    ((float4*)xrow)[t] = *(const float4*)(x + (size_t)row * DIM + 4 * t);
    __syncthreads();
    float bd = INFINITY; int bk = NCENT;
    for (int i = 0; i < NCENT / 256; ++i) {
      const int k = t + 256 * i;
      const float4* crow = (const float4*)(cent + (size_t)k * DIM);
      float a0 = 0.f, a1 = 0.f, a2 = 0.f, a3 = 0.f;
      float n0 = 0.f, n1 = 0.f, n2 = 0.f, n3 = 0.f;
#pragma unroll 8
      for (int j = 0; j < DIM / 4; ++j) {
        const float4 cv = crow[j];
        const float4 xv = ((const float4*)xrow)[j];
        a0 = fmaf(cv.x, xv.x, a0); n0 = fmaf(cv.x, cv.x, n0);
        a1 = fmaf(cv.y, xv.y, a1); n1 = fmaf(cv.y, cv.y, n1);
        a2 = fmaf(cv.z, xv.z, a2); n2 = fmaf(cv.z, cv.z, n2);
        a3 = fmaf(cv.w, xv.w, a3); n3 = fmaf(cv.w, cv.w, n3);
      }
      const float d = fmaf(-2.f, (a0 + a1) + (a2 + a3), (n0 + n1) + (n2 + n3));
      if (d < bd || (d == bd && k < bk)) { bd = d; bk = k; }
    }
#pragma unroll
    for (int off = 32; off > 0; off >>= 1) {
      const float od = __shfl_down(bd, off, 64);
      const int   ok = __shfl_down(bk, off, 64);
      if (od < bd || (od == bd && ok < bk)) { bd = od; bk = ok; }
    }
    if (lane == 0) { p2d[w] = bd; p2k[w] = bk; }
    __syncthreads();
    if (t == 0) {
      float fd = p2d[0]; int fk = p2k[0];
#pragma unroll
      for (int ww = 1; ww < 4; ++ww) {
        if (p2d[ww] < fd || (p2d[ww] == fd && p2k[ww] < fk)) {
          fd = p2d[ww]; fk = p2k[ww];
        }
      }
      out[row] = fk;
    }
    __syncthreads();
  }
}

// ---------------------------------------------------------------------------
// Fallback (verified, in-kernel split, 64 rows/block, KE=32) — used only if
// the workspace is too small for the pre-split centroid buffer.
// ---------------------------------------------------------------------------
__global__ void __launch_bounds__(256, 2) kmeans_mfma_fallback(
    const float* __restrict__ x, const float* __restrict__ cent,
    int* __restrict__ out) {
  __shared__ __align__(16) _Float16 cs[2][4][CS_KK][8];
  __shared__ __align__(16) _Float16 xs[2][4][XS_KK][8];
  __shared__ float nrm[256];
  __shared__ float sbest[MROWS_FB][4];
  __shared__ float sbest2[MROWS_FB][4];
  __shared__ int   sbidx[MROWS_FB][4];
  __shared__ int   sres[MROWS_FB];
  __shared__ int   sflag[MROWS_FB];
  __shared__ float p2d[4];
  __shared__ int   p2k[4];

  const int t    = threadIdx.x;
  const int lane = t & 63;
  const int w    = t >> 6;
  const int l31  = lane & 31;
  const int lhi  = lane >> 5;
  const size_t row0 = (size_t)blockIdx.x * MROWS_FB;

  float best[2]  = {INFINITY, INFINITY};
  float best2[2] = {INFINITY, INFINITY};
  int   bidx[2]  = {0, 0};

  for (int p = 0; p < 8; ++p) {
    const int kbase = p * 256;
    floatx16 acc[2][2] = {};
    float nacc[8] = {};

    for (int ec = 0; ec < 32; ++ec) {
      const int ebase = ec * 32;
      __syncthreads();
#pragma unroll
      for (int i = 0; i < 2; ++i) {
        const int idx = t + 256 * i;
        const int row = idx >> 3, e4 = idx & 7;
        const float4 v = *(const float4*)(x + (row0 + row) * DIM + ebase + 4 * e4);
        half4v h, l;
        split4_f16(v, h, l);
        *(half4v*)&xs[0][e4 >> 1][row][(e4 & 1) * 4] = h;
        *(half4v*)&xs[1][e4 >> 1][row][(e4 & 1) * 4] = l;
      }
#pragma unroll
      for (int i = 0; i < 8; ++i) {
        const int idx = t + 256 * i;
        const int kk = idx >> 3, e4 = idx & 7;
        const float4 v =
            *(const float4*)(cent + (size_t)(kbase + kk) * DIM + ebase + 4 * e4);
        nacc[i] = fmaf(v.x, v.x, nacc[i]); nacc[i] = fmaf(v.y, v.y, nacc[i]);
        nacc[i] = fmaf(v.z, v.z, nacc[i]); nacc[i] = fmaf(v.w, v.w, nacc[i]);
        half4v h, l;
        split4_f16(v, h, l);
        *(half4v*)&cs[0][e4 >> 1][kk][(e4 & 1) * 4] = h;
        *(half4v*)&cs[1][e4 >> 1][kk][(e4 & 1) * 4] = l;
      }
      __syncthreads();

#pragma unroll
      for (int es = 0; es < 2; ++es) {
        const int esub = es * 2 + lhi;
        half8v Ah[2], Al[2], Bh[2], Bl[2];
#pragma unroll
        for (int kt = 0; kt < 2; ++kt) {
          const int kk = w * 64 + kt * 32 + l31;
          Ah[kt] = *(const half8v*)&cs[0][esub][kk][0];
          Al[kt] = *(const half8v*)&cs[1][esub][kk][0];
        }
#pragma unroll
        for (int nt = 0; nt < 2; ++nt) {
          const int rr = nt * 32 + l31;
          Bh[nt] = *(const half8v*)&xs[0][esub][rr][0];
          Bl[nt] = *(const half8v*)&xs[1][esub][rr][0];
        }
#pragma unroll
        for (int kt = 0; kt < 2; ++kt)
#pragma unroll
          for (int nt = 0; nt < 2; ++nt) {
            acc[kt][nt] = __builtin_amdgcn_mfma_f32_32x32x16_f16(
                Ah[kt], Bh[nt], acc[kt][nt], 0, 0, 0);
            acc[kt][nt] = __builtin_amdgcn_mfma_f32_32x32x16_f16(
                Ah[kt], Bl[nt], acc[kt][nt], 0, 0, 0);
            acc[kt][nt] = __builtin_amdgcn_mfma_f32_32x32x16_f16(
                Al[kt], Bh[nt], acc[kt][nt], 0, 0, 0);
          }
      }
    }

#pragma unroll
    for (int i = 0; i < 8; ++i) {
      float n = nacc[i];
      n += __shfl_xor(n, 1, 64);
      n += __shfl_xor(n, 2, 64);
      n += __shfl_xor(n, 4, 64);
      if ((t & 7) == 0) nrm[(t >> 3) + 32 * i] = n;
    }
    __syncthreads();

#pragma unroll
    for (int kt = 0; kt < 2; ++kt) {
      const int kmb = w * 64 + kt * 32 + 4 * lhi;
#pragma unroll
      for (int r = 0; r < 16; ++r) {
        const int km = kmb + (r & 3) + 8 * (r >> 2);
        const float nk = nrm[km];
        const int kg = kbase + km;
#pragma unroll
        for (int nt = 0; nt < 2; ++nt) {
          const float d = fmaf(-2.0f, acc[kt][nt][r], nk);
          if (d < best[nt]) { best2[nt] = best[nt]; best[nt] = d; bidx[nt] = kg; }
          else best2[nt] = fminf(best2[nt], d);
        }
      }
    }
  }

#pragma unroll
  for (int nt = 0; nt < 2; ++nt) {
    float b = best[nt], b2 = best2[nt];
    int bi = bidx[nt];
    const float ob  = __shfl_xor(b, 32, 64);
    const float ob2 = __shfl_xor(b2, 32, 64);
    const int   obi = __shfl_xor(bi, 32, 64);
    const float nb2 = fminf(fminf(b2, ob2), fmaxf(b, ob));
    if (ob < b || (ob == b && obi < bi)) { b = ob; bi = obi; }
    if (lhi == 0) {
      const int row = nt * 32 + l31;
      sbest[row][w] = b; sbest2[row][w] = nb2; sbidx[row][w] = bi;
    }
  }
  __syncthreads();

  if (t < MROWS_FB) {
    float b = sbest[t][0], b2 = sbest2[t][0];
    int bi = sbidx[t][0];
#pragma unroll
    for (int ww = 1; ww < 4; ++ww) {
      const float cb = sbest[t][ww], cb2 = sbest2[t][ww];
      const int cbi = sbidx[t][ww];
      const float nb2 = fminf(fminf(b2, cb2), fmaxf(b, cb));
      if (cb < b || (cb == b && cbi < bi)) { b = cb; bi = cbi; }
      b2 = nb2;
    }
    sres[t] = bi;
    sflag[t] = (b2 - b < TAU) ? 1 : 0;
  }
  __syncthreads();

  float* xrw = (float*)&xs[0][0][0][0];
  for (int r = 0; r < MROWS_FB; ++r) {
    if (sflag[r]) {
      __syncthreads();
      for (int i = t; i < DIM / 4; i += 256)
        ((float4*)xrw)[i] = *(const float4*)(x + (row0 + r) * DIM + 4 * i);
      __syncthreads();
      float bd = INFINITY; int bk = NCENT;
      for (int i = 0; i < NCENT / 256; ++i) {
        const int k = t + 256 * i;
        const float4* crow = (const float4*)(cent + (size_t)k * DIM);
        float a0 = 0.f, a1 = 0.f, a2 = 0.f, a3 = 0.f;
        float n0 = 0.f, n1 = 0.f, n2 = 0.f, n3 = 0.f;
#pragma unroll 8
        for (int j = 0; j < DIM / 4; ++j) {
          const float4 cv = crow[j];
          const float4 xv = ((const float4*)xrw)[j];
          a0 = fmaf(cv.x, xv.x, a0); n0 = fmaf(cv.x, cv.x, n0);
          a1 = fmaf(cv.y, xv.y, a1); n1 = fmaf(cv.y, cv.y, n1);
          a2 = fmaf(cv.z, xv.z, a2); n2 = fmaf(cv.z, cv.z, n2);
          a3 = fmaf(cv.w, xv.w, a3); n3 = fmaf(cv.w, cv.w, n3);
        }
        const float d = fmaf(-2.f, (a0 + a1) + (a2 + a3), (n0 + n1) + (n2 + n3));
        if (d < bd || (d == bd && k < bk)) { bd = d; bk = k; }
      }
#pragma unroll
      for (int off = 32; off > 0; off >>= 1) {
        const float od = __shfl_down(bd, off, 64);
        const int   ok = __shfl_down(bk, off, 64);
        if (od < bd || (od == bd && ok < bk)) { bd = od; bk = ok; }
      }
      if (lane == 0) { p2d[w] = bd; p2k[w] = bk; }
      __syncthreads();
      if (t == 0) {
        float fd = p2d[0]; int fk = p2k[0];
#pragma unroll
        for (int ww = 1; ww < 4; ++ww) {
          if (p2d[ww] < fd || (p2d[ww] == fd && p2k[ww] < fk)) {
            fd = p2d[ww]; fk = p2k[ww];
          }
        }
        sres[r] = fk;
      }
      __syncthreads();
    }
  }
  __syncthreads();

  if (t < MROWS_FB) out[row0 + t] = sres[t];
}

extern "C" void kernel_launch(void* const* d_in, const int* in_sizes, int n_in,
                              void* d_out, int out_size, void* d_ws, size_t ws_size,
                              hipStream_t stream) {
  const float* x    = (const float*)d_in[0];   // [16,2000,1024] fp32
  const float* cent = (const float*)d_in[1];   // [2048,1024] fp32
  int* out = (int*)d_out;                      // 32000 int32 indices

  // Workspace layout: G | nrm | candb | candb2 | candi | cnt | list
  const size_t g_bytes    = (size_t)NCENT * DIM * 2 * sizeof(_Float16);  // 8 MB
  const size_t nrm_bytes  = (size_t)NCENT * sizeof(float);
  const size_t cand_elems = (size_t)N_ROWS * 2;
  const size_t cand_bytes = cand_elems * sizeof(float);
  const size_t need = g_bytes + nrm_bytes + 3 * cand_bytes +
                      sizeof(int) + (size_t)N_ROWS * sizeof(int);
  if (d_ws != nullptr && ws_size >= need) {
    char* p = (char*)d_ws;
    _Float16* G   = (_Float16*)p;            p += g_bytes;
    float* nrm_g  = (float*)p;               p += nrm_bytes;
    float* candb  = (float*)p;               p += cand_bytes;
    float* candb2 = (float*)p;               p += cand_bytes;
    int*   candi  = (int*)p;                 p += cand_bytes;
    int*   cnt    = (int*)p;                 p += sizeof(int);
    int*   list   = (int*)p;
    hipLaunchKernelGGL(kmeans_prep_kernel, dim3(NCENT), dim3(256), 0, stream,
                       cent, G, nrm_g, cnt);
    hipLaunchKernelGGL(kmeans_main_kernel, dim3((N_ROWS / MROWS) * 2), dim3(NTHR),
                       0, stream, x, G, nrm_g, candb, candb2, candi);
    hipLaunchKernelGGL(kmeans_merge_kernel, dim3((N_ROWS + 255) / 256), dim3(256),
                       0, stream, candb, candb2, candi, out, cnt, list);
    hipLaunchKernelGGL(kmeans_rescore_kernel, dim3(64), dim3(256), 0, stream,
                       x, cent, out, cnt, list);
  } else {
    hipLaunchKernelGGL(kmeans_mfma_fallback, dim3(N_ROWS / MROWS_FB), dim3(256), 0,
                       stream, x, cent, out);
  }
}